// Round 11
// baseline (1326.184 us; speedup 1.0000x reference)
//
#include <hip/hip_runtime.h>

// BiLSTM: B=512, T=200, E=H=128, 2 layers, bidir, residual on layer 1,
// out = 0.5*(fw+bw).
// Round 11: TWO-LAYER PIPELINED SCAN.  L1(tau) depends only on h0(tau) of the
// same direction/rows, so one block runs L0 step s and L1 step s-1 together:
//   z0(s)   = zx0(s) + U0*h0(s-1)                [zx0 from front GEMM]
//   z1(s-1) = b1 + W1*h0(s-1) + U1*h1(s-2)       [one ds_read of h0 feeds both]
// h0/h1 live ONLY in LDS (no h0 global round-trip, no L1 GEMM, no final_add);
// out accumulated via 2-way fp32 atomicAdd (deterministic).  Raw s_barrier +
// lgkmcnt(0) only; vmcnt never drained; zx register pipeline depth 2.
// Weights: aU0+aW1+aU1 = 192 stationary regs -> AGPR file (unified on gfx950).

typedef _Float16 f16;
typedef _Float16 f16x2 __attribute__((ext_vector_type(2)));
typedef _Float16 f16x4 __attribute__((ext_vector_type(4)));
typedef _Float16 f16x8 __attribute__((ext_vector_type(8)));
typedef float    f32x4 __attribute__((ext_vector_type(4)));

#define B_   512
#define T_   200
#define E_   128
#define H_   128
#define G4_  512
#define M_   (B_*T_)   // 102400

constexpr float NL2E  = -1.4426950408889634f;   // -log2(e)
constexpr float NL2E2 = -2.8853900817779268f;   // -2*log2(e)

static __device__ __forceinline__ float rcpa(float x) {
#if __has_builtin(__builtin_amdgcn_rcpf)
  return __builtin_amdgcn_rcpf(x);
#else
  return 1.f / x;
#endif
}
static __device__ __forceinline__ float exp2a(float x) {
#if __has_builtin(__builtin_amdgcn_exp2f)
  return __builtin_amdgcn_exp2f(x);
#else
  return exp2f(x);
#endif
}
static __device__ __forceinline__ f16x2 pk2(float lo, float hi) {
  return __builtin_bit_cast(f16x2, __builtin_amdgcn_cvt_pkrtz(lo, hi));
}
static __device__ __forceinline__ void lgkm_barrier() {
  asm volatile("s_waitcnt lgkmcnt(0)" ::: "memory");
  __builtin_amdgcn_s_barrier();
}

// ---------- prep: W,U [slab][128][512] f32 -> [slab][512][128] f16, scaled ----------
// 8 slabs: 4 of W ([L][dir]) then 4 of U.  All scaled by -log2e (g-gate cols
// 256..383 by -2log2e) so sigma(z) = rcp(1+exp2(z')).
__global__ __launch_bounds__(256)
void prep_w(const float* __restrict__ W, const float* __restrict__ U,
            f16* __restrict__ Wt, f16* __restrict__ Ut) {
  const int m = blockIdx.x;                     // 0..7
  const float* s = (m < 4 ? W + (size_t)m * E_ * G4_ : U + (size_t)(m - 4) * E_ * G4_);
  f16* d        = (m < 4 ? Wt + (size_t)m * E_ * G4_ : Ut + (size_t)(m - 4) * E_ * G4_);
  for (int i = threadIdx.x; i < E_ * G4_; i += 256) {
    const int k = i >> 9, g = i & 511;
    const float sc = ((g >> 7) == 2) ? NL2E2 : NL2E;
    d[(size_t)g * E_ + k] = (f16)(s[i] * sc);
  }
}

// ---------------- GEMM: zx[dir][m][g] = (x[m][:] @ W0[:][g] + b0[g]) * sc(g) ----------------
// grid (512/64, M/128, 2), block 256.  Tile 128(M) x 64(N), K=128 in LDS.
__global__ __launch_bounds__(256)
void gemm_zx(const float* __restrict__ A,
             const float* __restrict__ Wl,   // [2][128][512] layer 0 (raw)
             const float* __restrict__ bl,   // [2][512] layer 0 (raw)
             f16* __restrict__ zx)           // [2][M][512]
{
  __shared__ f16 Ash[128 * 136];
  __shared__ f16 Bsh[64 * 136];    // transposed: [n][k], scaled

  const int n0  = blockIdx.x * 64;
  const int m0  = blockIdx.y * 128;
  const int dir = blockIdx.z;
  const float* Wd = Wl + (size_t)dir * E_ * G4_;
  const float* bd = bl + (size_t)dir * G4_;
  const int tid = threadIdx.x;

#pragma unroll
  for (int it = 0; it < 16; ++it) {
    int idx = tid + it * 256;
    int row = idx >> 5, c4 = idx & 31;
    const float4 v = *(const float4*)(A + (size_t)(m0 + row) * E_ + c4 * 4);
    f16x2 p0; p0[0] = (f16)v.x; p0[1] = (f16)v.y;
    f16x2 p1; p1[0] = (f16)v.z; p1[1] = (f16)v.w;
    uint2 w2; w2.x = __builtin_bit_cast(unsigned int, p0); w2.y = __builtin_bit_cast(unsigned int, p1);
    *(uint2*)&Ash[row * 136 + c4 * 4] = w2;
  }
#pragma unroll
  for (int it = 0; it < 8; ++it) {
    int idx = tid + it * 256;
    int k = idx >> 4, n4 = idx & 15;
    const int g = n0 + n4 * 4;
    const float sc = ((g >> 7) == 2) ? NL2E2 : NL2E;
    const float4 v = *(const float4*)(Wd + (size_t)k * G4_ + g);
    Bsh[(n4 * 4 + 0) * 136 + k] = (f16)(v.x * sc);
    Bsh[(n4 * 4 + 1) * 136 + k] = (f16)(v.y * sc);
    Bsh[(n4 * 4 + 2) * 136 + k] = (f16)(v.z * sc);
    Bsh[(n4 * 4 + 3) * 136 + k] = (f16)(v.w * sc);
  }
  __syncthreads();

  const int w = tid >> 6, l = tid & 63;
  const int lr = l & 15, lk = (l >> 4) * 8;
  f32x4 acc[2][4] = {};

#pragma unroll
  for (int kc = 0; kc < 4; ++kc) {
    const int kb = kc * 32 + lk;
    f16x8 a0 = *(const f16x8*)&Ash[(w * 32 + 0  + lr) * 136 + kb];
    f16x8 a1 = *(const f16x8*)&Ash[(w * 32 + 16 + lr) * 136 + kb];
    f16x8 b0 = *(const f16x8*)&Bsh[(0  + lr) * 136 + kb];
    f16x8 b1 = *(const f16x8*)&Bsh[(16 + lr) * 136 + kb];
    f16x8 b2 = *(const f16x8*)&Bsh[(32 + lr) * 136 + kb];
    f16x8 b3 = *(const f16x8*)&Bsh[(48 + lr) * 136 + kb];
    acc[0][0] = __builtin_amdgcn_mfma_f32_16x16x32_f16(a0, b0, acc[0][0], 0, 0, 0);
    acc[0][1] = __builtin_amdgcn_mfma_f32_16x16x32_f16(a0, b1, acc[0][1], 0, 0, 0);
    acc[0][2] = __builtin_amdgcn_mfma_f32_16x16x32_f16(a0, b2, acc[0][2], 0, 0, 0);
    acc[0][3] = __builtin_amdgcn_mfma_f32_16x16x32_f16(a0, b3, acc[0][3], 0, 0, 0);
    acc[1][0] = __builtin_amdgcn_mfma_f32_16x16x32_f16(a1, b0, acc[1][0], 0, 0, 0);
    acc[1][1] = __builtin_amdgcn_mfma_f32_16x16x32_f16(a1, b1, acc[1][1], 0, 0, 0);
    acc[1][2] = __builtin_amdgcn_mfma_f32_16x16x32_f16(a1, b2, acc[1][2], 0, 0, 0);
    acc[1][3] = __builtin_amdgcn_mfma_f32_16x16x32_f16(a1, b3, acc[1][3], 0, 0, 0);
  }

#pragma unroll
  for (int mf = 0; mf < 2; ++mf) {
#pragma unroll
    for (int nf = 0; nf < 4; ++nf) {
      const int g = n0 + nf * 16 + lr;
      const float sc = ((g >> 7) == 2) ? NL2E2 : NL2E;
      const float bias = bd[g] * sc;
#pragma unroll
      for (int i = 0; i < 4; ++i) {
        const int m = m0 + w * 32 + mf * 16 + (l >> 4) * 4 + i;
        zx[((size_t)dir * M_ + m) * G4_ + g] = (f16)(acc[mf][nf][i] + bias);
      }
    }
  }
}

// ---------------- fused two-layer pipelined scan ----------------
// grid 64: dir = bx>>5, rows [R0, R0+16).  block 512 = 8 waves.
// Wave wv owns gate-cols {g*128 + wv*16 + c} for BOTH layers.  Lane l:
// batch row l&15, kg = l>>4, cells kg*4+i of hidden slice [wv*16,+16).
__global__ __launch_bounds__(512, 2)
void scan2(const f16* __restrict__ zx,     // [2][M][512] L0 input proj (scaled)
           const f16* __restrict__ Ut0,    // [512][128] per dir stride: layer0 U^T
           const f16* __restrict__ Wt1,    // layer1 W^T
           const f16* __restrict__ Ut1,    // layer1 U^T
           const float* __restrict__ b1,   // [2][512] layer 1 (raw)
           float* __restrict__ out)        // [M][128] f32, zeroed; 2-way atomicAdd
{
  __shared__ f16 hsh0[2][16][136];
  __shared__ f16 hsh1[2][16][136];

  const int tid  = threadIdx.x;
  const int lane = tid & 63;
  const int wv   = tid >> 6;
  const int row  = lane & 15;
  const int kg   = lane >> 4;
  const int bx   = blockIdx.x;
  const int dir  = bx >> 5;
  const int R0   = (bx & 31) * 16;
  const int coff = wv * 16 + kg * 4;

  const f16* U0d = Ut0 + (size_t)dir * G4_ * E_;
  const f16* W1d = Wt1 + (size_t)dir * G4_ * E_;
  const f16* U1d = Ut1 + (size_t)dir * G4_ * E_;
  const float* b1d = b1 + (size_t)dir * G4_;
  const f16* zxd = zx + (size_t)dir * M_ * G4_;

  // stationary A-frags (-> AGPRs): 3 matrices x 16 x f16x8 = 192 regs
  f16x8 aU0[4][4], aW1[4][4], aU1[4][4];
#pragma unroll
  for (int g = 0; g < 4; ++g) {
    const size_t gcol = (size_t)(g * 128 + wv * 16 + row) * E_;
#pragma unroll
    for (int kk = 0; kk < 4; ++kk) {
      aU0[g][kk] = *(const f16x8*)(U0d + gcol + kk * 32 + kg * 8);
      aW1[g][kk] = *(const f16x8*)(W1d + gcol + kk * 32 + kg * 8);
      aU1[g][kk] = *(const f16x8*)(U1d + gcol + kk * 32 + kg * 8);
    }
  }
  // L1 bias, scaled (g-gate x2)
  f32x4 zb1[4];
#pragma unroll
  for (int g = 0; g < 4; ++g) {
#pragma unroll
    for (int i = 0; i < 4; ++i) {
      const float v = b1d[g * 128 + coff + i];
      zb1[g][i] = v * ((g == 2) ? NL2E2 : NL2E);
    }
  }

  // zero all h buffers (h0(-1)=h1(-1)=0)
  for (int i = tid; i < 2 * 16 * 136; i += 512) {
    ((f16*)hsh0)[i] = (f16)0.f;
    ((f16*)hsh1)[i] = (f16)0.f;
  }

  const int t0 = dir ? (T_ - 1) : 0;
  const int ts = dir ? -1 : 1;

  // zx register pipelines, depth 2 (A: even s, B: odd s)
  const f16* zbase = zxd + ((size_t)(R0 + row) * T_ + t0) * G4_ + coff;
  const f16* zptrA = zbase;
  const f16* zptrB = zbase + (long)ts * G4_;
  f16x4 zpA[4], zpB[4];
#pragma unroll
  for (int g = 0; g < 4; ++g) {
    zpA[g] = *(const f16x4*)(zptrA + g * 128);
    zpB[g] = *(const f16x4*)(zptrB + g * 128);
  }
  float* outp = out + (size_t)(R0 + row) * T_ * H_ + (size_t)t0 * H_ + coff;

  float cc0[4] = {0.f, 0.f, 0.f, 0.f};
  float cc1[4] = {0.f, 0.f, 0.f, 0.f};

  auto gates = [&](f32x4 (&z)[4], float (&cc)[4], float (&hv)[4]) {
#pragma unroll
    for (int i = 0; i < 4; ++i) {
      const float ig = rcpa(1.f + exp2a(z[0][i]));
      const float fg = rcpa(1.f + exp2a(z[1][i]));
      const float gg = fmaf(2.f, rcpa(1.f + exp2a(z[2][i])), -1.f);
      const float og = rcpa(1.f + exp2a(z[3][i]));
      cc[i] = fmaf(fg, cc[i], ig * gg);
      const float tc = fmaf(2.f, rcpa(1.f + exp2a(cc[i] * NL2E2)), -1.f);
      hv[i] = og * tc;
    }
  };

  lgkm_barrier();   // h zeros visible

  // ---- s = 0: L0 only; h0(-1)=0 so z0 = zx(t0) exactly ----
  {
    f32x4 z0[4];
#pragma unroll
    for (int g = 0; g < 4; ++g) {
#pragma unroll
      for (int i = 0; i < 4; ++i) z0[g][i] = (float)zpA[g][i];
    }
    float hv0[4];
    gates(z0, cc0, hv0);
    const f16x2 h01 = pk2(hv0[0], hv0[1]);
    const f16x2 h23 = pk2(hv0[2], hv0[3]);
    uint2 hp;
    hp.x = __builtin_bit_cast(unsigned int, h01);
    hp.y = __builtin_bit_cast(unsigned int, h23);
    *(uint2*)&hsh0[1][row][coff] = hp;
    zptrA += 2 * ts * G4_;
#pragma unroll
    for (int g = 0; g < 4; ++g) zpA[g] = *(const f16x4*)(zptrA + g * 128);
    lgkm_barrier();
  }

  // ---- main: s = 1..200 ----
  auto step = [&](f16x4 (&zp)[4], const f16*& zptr, int p, bool do0) {
    // shared ds_read of h0(s-1): feeds U0 (L0) and W1 (L1); h1(s-2) for U1;
    // residual h0(s-1)[coff..] for the output.
    f16x8 hf0[4], hf1[4];
#pragma unroll
    for (int kk = 0; kk < 4; ++kk) hf0[kk] = *(const f16x8*)&hsh0[p][row][kk * 32 + kg * 8];
#pragma unroll
    for (int kk = 0; kk < 4; ++kk) hf1[kk] = *(const f16x8*)&hsh1[p][row][kk * 32 + kg * 8];
    const uint2 resv = *(const uint2*)&hsh0[p][row][coff];

    // L1: z1 = b1' + W1'*h0(s-1) + U1'*h1(s-2)
    f32x4 z1[4];
#pragma unroll
    for (int g = 0; g < 4; ++g)
      z1[g] = __builtin_amdgcn_mfma_f32_16x16x32_f16(aW1[g][0], hf0[0], zb1[g], 0, 0, 0);
#pragma unroll
    for (int kk = 1; kk < 4; ++kk) {
      z1[0] = __builtin_amdgcn_mfma_f32_16x16x32_f16(aW1[0][kk], hf0[kk], z1[0], 0, 0, 0);
      z1[1] = __builtin_amdgcn_mfma_f32_16x16x32_f16(aW1[1][kk], hf0[kk], z1[1], 0, 0, 0);
      z1[2] = __builtin_amdgcn_mfma_f32_16x16x32_f16(aW1[2][kk], hf0[kk], z1[2], 0, 0, 0);
      z1[3] = __builtin_amdgcn_mfma_f32_16x16x32_f16(aW1[3][kk], hf0[kk], z1[3], 0, 0, 0);
    }
#pragma unroll
    for (int kk = 0; kk < 4; ++kk) {
      z1[0] = __builtin_amdgcn_mfma_f32_16x16x32_f16(aU1[0][kk], hf1[kk], z1[0], 0, 0, 0);
      z1[1] = __builtin_amdgcn_mfma_f32_16x16x32_f16(aU1[1][kk], hf1[kk], z1[1], 0, 0, 0);
      z1[2] = __builtin_amdgcn_mfma_f32_16x16x32_f16(aU1[2][kk], hf1[kk], z1[2], 0, 0, 0);
      z1[3] = __builtin_amdgcn_mfma_f32_16x16x32_f16(aU1[3][kk], hf1[kk], z1[3], 0, 0, 0);
    }

    // L0 (skipped at s=200): z0 = zx(s) + U0'*h0(s-1)
    if (do0) {
      f32x4 z0[4];
#pragma unroll
      for (int g = 0; g < 4; ++g) {
#pragma unroll
        for (int i = 0; i < 4; ++i) z0[g][i] = (float)zp[g][i];
      }
#pragma unroll
      for (int kk = 0; kk < 4; ++kk) {
        z0[0] = __builtin_amdgcn_mfma_f32_16x16x32_f16(aU0[0][kk], hf0[kk], z0[0], 0, 0, 0);
        z0[1] = __builtin_amdgcn_mfma_f32_16x16x32_f16(aU0[1][kk], hf0[kk], z0[1], 0, 0, 0);
        z0[2] = __builtin_amdgcn_mfma_f32_16x16x32_f16(aU0[2][kk], hf0[kk], z0[2], 0, 0, 0);
        z0[3] = __builtin_amdgcn_mfma_f32_16x16x32_f16(aU0[3][kk], hf0[kk], z0[3], 0, 0, 0);
      }
      float hv0[4];
      gates(z0, cc0, hv0);
      const f16x2 h01 = pk2(hv0[0], hv0[1]);
      const f16x2 h23 = pk2(hv0[2], hv0[3]);
      uint2 hp;
      hp.x = __builtin_bit_cast(unsigned int, h01);
      hp.y = __builtin_bit_cast(unsigned int, h23);
      *(uint2*)&hsh0[p ^ 1][row][coff] = hp;
      // refill zx(s+2)
      zptr += 2 * ts * G4_;
#pragma unroll
      for (int g = 0; g < 4; ++g) zp[g] = *(const f16x4*)(zptr + g * 128);
    }

    // L1 gates + h1 exchange + output
    float hv1[4];
    gates(z1, cc1, hv1);
    const f16x2 g01 = pk2(hv1[0], hv1[1]);
    const f16x2 g23 = pk2(hv1[2], hv1[3]);
    uint2 hq;
    hq.x = __builtin_bit_cast(unsigned int, g01);
    hq.y = __builtin_bit_cast(unsigned int, g23);
    *(uint2*)&hsh1[p ^ 1][row][coff] = hq;

    const f16x2 r01 = __builtin_bit_cast(f16x2, resv.x);
    const f16x2 r23 = __builtin_bit_cast(f16x2, resv.y);
    atomicAdd(outp + 0, 0.5f * (hv1[0] + (float)r01[0]));
    atomicAdd(outp + 1, 0.5f * (hv1[1] + (float)r01[1]));
    atomicAdd(outp + 2, 0.5f * (hv1[2] + (float)r23[0]));
    atomicAdd(outp + 3, 0.5f * (hv1[3] + (float)r23[1]));
    outp += ts * H_;

    lgkm_barrier();   // h(t) visible; vmcnt NOT drained
  };

  for (int k = 0; k < 100; ++k) {
    step(zpB, zptrB, 1, true);       // s = 2k+1
    step(zpA, zptrA, 0, k != 99);    // s = 2k+2 (L0 off at s=200)
  }
}

extern "C" void kernel_launch(void* const* d_in, const int* in_sizes, int n_in,
                              void* d_out, int out_size, void* d_ws, size_t ws_size,
                              hipStream_t stream) {
  const float* x = (const float*)d_in[0];
  const float* W = (const float*)d_in[1];  // [2][2][128][512]
  const float* U = (const float*)d_in[2];  // [2][2][128][512]
  const float* b = (const float*)d_in[3];  // [2][2][512]
  float* out = (float*)d_out;

  char* ws = (char*)d_ws;
  f16* zx = (f16*)ws;                               // [2][M][512] = 209,715,200 B
  f16* Wt = (f16*)(ws + (size_t)2 * M_ * G4_ * 2);  // [4][512][128] f16 = 524,288 B
  f16* Ut = Wt + (size_t)4 * G4_ * E_;              // [4][512][128] f16 = 524,288 B
  // zx tail prefetch overruns (<=2KB) land in Wt -- valid memory, never used.

  const size_t SL = (size_t)2 * G4_ * E_;   // f16 per layer of Wt/Ut
  const size_t BL = 2 * G4_;

  hipMemsetAsync(d_out, 0, (size_t)out_size * sizeof(float), stream);
  prep_w<<<dim3(8), 256, 0, stream>>>(W, U, Wt, Ut);
  gemm_zx<<<dim3(G4_ / 64, M_ / 128, 2), 256, 0, stream>>>(x, W, b, zx);
  scan2<<<dim3(64), 512, 0, stream>>>(zx, Ut, Wt + SL, Ut + SL, b + BL, out);
}

// Round 12
// 709.268 us; speedup vs baseline: 1.8698x; 1.8698x over previous
//
#include <hip/hip_runtime.h>

// BiLSTM: B=512, T=200, E=H=128, 2 layers, bidir, residual on layer 1,
// out = 0.5*(fw+bw).
// Round 12: 4-WAVE BLOCKS (256 thr), 1 wave/SIMD.  Hypothesis test: the
// ~2300 cyc/step unexplained overhead is 8-wave barrier skew + 2-wave/SIMD
// arbitration + AGPR-offload copies (demand ~240 > 128 fair share).  With 4
// waves: same per-SIMD issue work, half the barrier width, ~512-reg budget
// (stationary U+W frags in true VGPRs, ~424 demand < 450 no-spill line).
// Wave wv owns 32 cells = 128 gate-cols (2 column-tiles) x 16 rows.
// Everything else = round-5/7 verified structure: raw s_barrier+lgkmcnt(0)
// (vmcnt never drained), depth-2 x register pipeline, trans-pipe gates with
// -log2e folded into weights/bias (g-gate x2; R8-verified math).

typedef _Float16 f16;
typedef _Float16 f16x2 __attribute__((ext_vector_type(2)));
typedef _Float16 f16x4 __attribute__((ext_vector_type(4)));
typedef _Float16 f16x8 __attribute__((ext_vector_type(8)));
typedef float    f32x4 __attribute__((ext_vector_type(4)));

#define B_   512
#define T_   200
#define E_   128
#define H_   128
#define G4_  512
#define M_   (B_*T_)   // 102400

constexpr float NL2E  = -1.4426950408889634f;   // -log2(e)
constexpr float NL2E2 = -2.8853900817779268f;   // -2*log2(e)

static __device__ __forceinline__ float rcpa(float x) {
#if __has_builtin(__builtin_amdgcn_rcpf)
  return __builtin_amdgcn_rcpf(x);
#else
  return 1.f / x;
#endif
}
static __device__ __forceinline__ float exp2a(float x) {
#if __has_builtin(__builtin_amdgcn_exp2f)
  return __builtin_amdgcn_exp2f(x);
#else
  return exp2f(x);
#endif
}
static __device__ __forceinline__ f16x2 pk2(float lo, float hi) {
  return __builtin_bit_cast(f16x2, __builtin_amdgcn_cvt_pkrtz(lo, hi));
}
static __device__ __forceinline__ void lgkm_barrier() {
  asm volatile("s_waitcnt lgkmcnt(0)" ::: "memory");
  __builtin_amdgcn_s_barrier();
}

// ---------- prep: x fp32 -> f16 ----------
__global__ __launch_bounds__(256)
void cvt_x(const float* __restrict__ x, f16* __restrict__ xh) {
  const int n8 = M_ * E_ / 8;
  for (int i = blockIdx.x * 256 + threadIdx.x; i < n8; i += gridDim.x * 256) {
    const float4 a = ((const float4*)x)[i * 2];
    const float4 b = ((const float4*)x)[i * 2 + 1];
    f16x8 v;
    v[0] = (f16)a.x; v[1] = (f16)a.y; v[2] = (f16)a.z; v[3] = (f16)a.w;
    v[4] = (f16)b.x; v[5] = (f16)b.y; v[6] = (f16)b.z; v[7] = (f16)b.w;
    *(f16x8*)(xh + (size_t)i * 8) = v;
  }
}

// ---------- prep: W,U [slab][128][512] f32 -> [slab][512][128] f16, scaled ----------
// 8 slabs: 4 of W then 4 of U.  Scaled by -log2e (g-gate cols 256..383 by
// -2log2e) so sigma(z) = rcp(1+exp2(z')) with no per-step multiply.
__global__ __launch_bounds__(256)
void prep_w(const float* __restrict__ W, const float* __restrict__ U,
            f16* __restrict__ Wt, f16* __restrict__ Ut) {
  const int m = blockIdx.x;                     // 0..7
  const float* s = (m < 4 ? W + (size_t)m * E_ * G4_ : U + (size_t)(m - 4) * E_ * G4_);
  f16* d        = (m < 4 ? Wt + (size_t)m * E_ * G4_ : Ut + (size_t)(m - 4) * E_ * G4_);
  for (int i = threadIdx.x; i < E_ * G4_; i += 256) {
    const int k = i >> 9, g = i & 511;
    const float sc = ((g >> 7) == 2) ? NL2E2 : NL2E;
    d[(size_t)g * E_ + k] = (f16)(s[i] * sc);
  }
}

// ---------- fused recurrent scan ----------
// grid 64: dir = bx>>5, rows [R0, R0+16).  block 256 = 4 waves, 1 wave/SIMD.
// Wave wv owns cells [wv*32, wv*32+32) as 2 column-tiles (ct=0,1).  Lane l:
// batch row l&15, kg = l>>4, cells {wv*32 + ct*16 + kg*4 + i}.
template <int LAYER>
__global__ __launch_bounds__(256, 1)
void scan_fused(const f16* __restrict__ in,    // L0: xh [M][128]; L1: h0 [2][M][128]
                const f16* __restrict__ Utl,   // [2][512][128] (transposed, scaled)
                const f16* __restrict__ Wtl,   // [2][512][128] (transposed, scaled)
                const float* __restrict__ bl,  // [2][512] this layer (raw)
                const f16* __restrict__ res,   // L1: h0 [2][M][128]
                f16* __restrict__ hout)        // [2][M][128]
{
  __shared__ f16 hsh[2][16][136];

  const int tid  = threadIdx.x;
  const int lane = tid & 63;
  const int wv   = tid >> 6;        // 0..3
  const int row  = lane & 15;
  const int kg   = lane >> 4;
  const int bx   = blockIdx.x;
  const int dir  = bx >> 5;
  const int R0   = (bx & 31) * 16;
  const int c0   = wv * 32 + kg * 4;      // tile-0 cell offset
  // tile-1 cells at c0 + 16

  const f16* Ud = Utl + (size_t)dir * G4_ * E_;
  const f16* Wd = Wtl + (size_t)dir * G4_ * E_;
  const float* bd = bl + (size_t)dir * G4_;
  const f16* ind  = in + (LAYER == 1 ? (size_t)dir * M_ * H_ : 0);
  f16* houtd      = hout + (size_t)dir * M_ * H_;

  // stationary A-frags: [gate][ctile][kchunk], 2x128 regs (fits 1-wave/SIMD budget)
  f16x8 aU[4][2][4], aW[4][2][4];
#pragma unroll
  for (int g = 0; g < 4; ++g) {
#pragma unroll
    for (int ct = 0; ct < 2; ++ct) {
      const size_t gcol = (size_t)(g * 128 + wv * 32 + ct * 16 + row) * E_;
#pragma unroll
      for (int kk = 0; kk < 4; ++kk) {
        aU[g][ct][kk] = *(const f16x8*)(Ud + gcol + kk * 32 + kg * 8);
        aW[g][ct][kk] = *(const f16x8*)(Wd + gcol + kk * 32 + kg * 8);
      }
    }
  }
  // bias, scaled (g-gate -2log2e); MFMA C-init each step
  f32x4 zb[4][2];
#pragma unroll
  for (int g = 0; g < 4; ++g) {
#pragma unroll
    for (int ct = 0; ct < 2; ++ct) {
#pragma unroll
      for (int i = 0; i < 4; ++i) {
        const float v = bd[g * 128 + wv * 32 + ct * 16 + kg * 4 + i];
        zb[g][ct][i] = v * ((g == 2) ? NL2E2 : NL2E);
      }
    }
  }

  // zero h(-1)
  for (int i = tid; i < 2 * 16 * 136; i += 256) ((f16*)hsh)[i] = (f16)0.f;

  const int t0 = dir ? (T_ - 1) : 0;
  const int ts = dir ? -1 : 1;

  const f16* inrow  = ind + (size_t)(R0 + row) * T_ * E_ + kg * 8;
  const f16* resrow = (LAYER == 1)
      ? res + (size_t)dir * M_ * H_ + (size_t)(R0 + row) * T_ * H_ + c0 : nullptr;
  f16* outptr = houtd + (size_t)(R0 + row) * T_ * H_ + (size_t)t0 * H_ + c0;

  float cc[8] = {0.f, 0.f, 0.f, 0.f, 0.f, 0.f, 0.f, 0.f};

  // depth-2 x register pipelines (A: even s, B: odd s)
  const f16* xptrA = inrow + (long)t0 * E_;
  const f16* xptrB = inrow + (long)(t0 + ts) * E_;
  f16x8 xpA[4], xpB[4];
#pragma unroll
  for (int kk = 0; kk < 4; ++kk) {
    xpA[kk] = *(const f16x8*)(xptrA + kk * 32);
    xpB[kk] = *(const f16x8*)(xptrB + kk * 32);
  }
  const f16* rptrA = nullptr; const f16* rptrB = nullptr;
  uint2 rvA[2] = {}, rvB[2] = {};
  if (LAYER == 1) {
    rptrA = resrow + (long)t0 * H_;
    rptrB = resrow + (long)(t0 + ts) * H_;
    rvA[0] = *(const uint2*)rptrA;      rvA[1] = *(const uint2*)(rptrA + 16);
    rvB[0] = *(const uint2*)rptrB;      rvB[1] = *(const uint2*)(rptrB + 16);
  }

  lgkm_barrier();   // hsh zero visible

  auto step = [&](f16x8 (&xp)[4], const f16*& xptr, uint2 (&rv)[2],
                  const f16*& rptr, int rp, int wp) {
    // (1) h(t-1) ds_reads first
    f16x8 hf[4];
#pragma unroll
    for (int kk = 0; kk < 4; ++kk) hf[kk] = *(const f16x8*)&hsh[rp][row][kk * 32 + kg * 8];

    // (2) consume x pipe regs; stash residual
    f16x8 xf[4];
#pragma unroll
    for (int kk = 0; kk < 4; ++kk) xf[kk] = xp[kk];
    f16x2 rva[2], rvb[2];
    if (LAYER == 1) {
#pragma unroll
      for (int ct = 0; ct < 2; ++ct) {
        rva[ct] = __builtin_bit_cast(f16x2, rv[ct].x);
        rvb[ct] = __builtin_bit_cast(f16x2, rv[ct].y);
      }
    }

    // (3) refill pipes for t+2
    xptr += 2 * ts * E_;
#pragma unroll
    for (int kk = 0; kk < 4; ++kk) xp[kk] = *(const f16x8*)(xptr + kk * 32);
    if (LAYER == 1) {
      rptr += 2 * ts * H_;
      rv[0] = *(const uint2*)rptr;
      rv[1] = *(const uint2*)(rptr + 16);
    }

    // (4) z = b' + W'*x(t) + U'*h(t-1)   (64 MFMAs)
    f32x4 z[4][2];
#pragma unroll
    for (int g = 0; g < 4; ++g) {
#pragma unroll
      for (int ct = 0; ct < 2; ++ct)
        z[g][ct] = __builtin_amdgcn_mfma_f32_16x16x32_f16(aW[g][ct][0], xf[0], zb[g][ct], 0, 0, 0);
    }
#pragma unroll
    for (int kk = 1; kk < 4; ++kk) {
#pragma unroll
      for (int g = 0; g < 4; ++g) {
#pragma unroll
        for (int ct = 0; ct < 2; ++ct)
          z[g][ct] = __builtin_amdgcn_mfma_f32_16x16x32_f16(aW[g][ct][kk], xf[kk], z[g][ct], 0, 0, 0);
      }
    }
#pragma unroll
    for (int kk = 0; kk < 4; ++kk) {
#pragma unroll
      for (int g = 0; g < 4; ++g) {
#pragma unroll
        for (int ct = 0; ct < 2; ++ct)
          z[g][ct] = __builtin_amdgcn_mfma_f32_16x16x32_f16(aU[g][ct][kk], hf[kk], z[g][ct], 0, 0, 0);
      }
    }

    // (5) gates for 8 cells: sigma = rcp(1+exp2(z')) (weights pre-scaled)
    float hv[8];
#pragma unroll
    for (int ct = 0; ct < 2; ++ct) {
#pragma unroll
      for (int i = 0; i < 4; ++i) {
        const int c = ct * 4 + i;
        const float ig = rcpa(1.f + exp2a(z[0][ct][i]));
        const float fg = rcpa(1.f + exp2a(z[1][ct][i]));
        const float gg = fmaf(2.f, rcpa(1.f + exp2a(z[2][ct][i])), -1.f);
        const float og = rcpa(1.f + exp2a(z[3][ct][i]));
        cc[c] = fmaf(fg, cc[c], ig * gg);
        const float tc = fmaf(2.f, rcpa(1.f + exp2a(cc[c] * NL2E2)), -1.f);
        hv[c] = og * tc;
      }
    }

    // (6) pack + h exchange + output store (pre-barrier)
    uint2 hp[2];
#pragma unroll
    for (int ct = 0; ct < 2; ++ct) {
      const f16x2 h01 = pk2(hv[ct * 4 + 0], hv[ct * 4 + 1]);
      const f16x2 h23 = pk2(hv[ct * 4 + 2], hv[ct * 4 + 3]);
      hp[ct].x = __builtin_bit_cast(unsigned int, h01);
      hp[ct].y = __builtin_bit_cast(unsigned int, h23);
    }
    *(uint2*)&hsh[wp][row][c0]      = hp[0];
    *(uint2*)&hsh[wp][row][c0 + 16] = hp[1];

    if (LAYER == 0) {
      *(uint2*)outptr        = hp[0];
      *(uint2*)(outptr + 16) = hp[1];
    } else {
      const f16x2 half2 = {(f16)0.5f, (f16)0.5f};
#pragma unroll
      for (int ct = 0; ct < 2; ++ct) {
        const f16x2 o01 = (__builtin_bit_cast(f16x2, hp[ct].x) + rva[ct]) * half2;
        const f16x2 o23 = (__builtin_bit_cast(f16x2, hp[ct].y) + rvb[ct]) * half2;
        uint2 o;
        o.x = __builtin_bit_cast(unsigned int, o01);
        o.y = __builtin_bit_cast(unsigned int, o23);
        *(uint2*)(outptr + ct * 16) = o;
      }
    }
    outptr += ts * H_;

    lgkm_barrier();   // h(t) visible; vmcnt NOT drained
  };

  for (int k = 0; k < T_ / 2; ++k) {
    step(xpA, xptrA, rvA, rptrA, k == 0 ? 0 : 0, 1);   // even s reads hsh[0], writes hsh[1]
    step(xpB, xptrB, rvB, rptrB, 1, 0);                // odd  s reads hsh[1], writes hsh[0]
  }
}

__global__ __launch_bounds__(256)
void final_add(const f16* __restrict__ a, const f16* __restrict__ b,
               float* __restrict__ o)
{
  const int n8 = M_ * H_ / 8;
  for (int i = blockIdx.x * 256 + threadIdx.x; i < n8; i += gridDim.x * 256) {
    const f16x8 va = *(const f16x8*)(a + (size_t)i * 8);
    const f16x8 vb = *(const f16x8*)(b + (size_t)i * 8);
    float4 o0, o1;
    o0.x = (float)va[0] + (float)vb[0];  o0.y = (float)va[1] + (float)vb[1];
    o0.z = (float)va[2] + (float)vb[2];  o0.w = (float)va[3] + (float)vb[3];
    o1.x = (float)va[4] + (float)vb[4];  o1.y = (float)va[5] + (float)vb[5];
    o1.z = (float)va[6] + (float)vb[6];  o1.w = (float)va[7] + (float)vb[7];
    *(float4*)(o + (size_t)i * 8)     = o0;
    *(float4*)(o + (size_t)i * 8 + 4) = o1;
  }
}

extern "C" void kernel_launch(void* const* d_in, const int* in_sizes, int n_in,
                              void* d_out, int out_size, void* d_ws, size_t ws_size,
                              hipStream_t stream) {
  const float* x = (const float*)d_in[0];
  const float* W = (const float*)d_in[1];  // [2][2][128][512]
  const float* U = (const float*)d_in[2];  // [2][2][128][512]
  const float* b = (const float*)d_in[3];  // [2][2][512]
  float* out = (float*)d_out;

  char* ws = (char*)d_ws;
  // 2KB guards around xh/h0/h1: register pipelines prefetch up to 2
  // timesteps (512B) past either end of a row.
  f16* xh = (f16*)(ws + 2048);                     // [M][128]    26.2 MB
  f16* h0 = xh + (size_t)M_ * E_ + 1024;           // [2][M][128] 52.4 MB (+2KB guard)
  f16* h1 = h0 + (size_t)2 * M_ * H_ + 1024;       // [2][M][128] 52.4 MB (+2KB guard)
  f16* Wt = h1 + (size_t)2 * M_ * H_ + 1024;       // [2][2][512][128] 1 MB
  f16* Ut = Wt + (size_t)4 * G4_ * E_;             // [2][2][512][128] 1 MB

  const size_t WTL = (size_t)2 * G4_ * E_;         // f16 per layer of Wt/Ut
  const size_t BL  = 2 * G4_;

  cvt_x<<<dim3(2048), 256, 0, stream>>>(x, xh);
  prep_w<<<dim3(8), 256, 0, stream>>>(W, U, Wt, Ut);
  scan_fused<0><<<dim3(64), 256, 0, stream>>>(xh, Ut, Wt, b, nullptr, h0);
  scan_fused<1><<<dim3(64), 256, 0, stream>>>(h0, Ut + WTL, Wt + WTL, b + BL, h0, h1);
  final_add<<<dim3(2048), 256, 0, stream>>>(h1, h1 + (size_t)M_ * H_, out);
}

// Round 13
// 610.651 us; speedup vs baseline: 2.1718x; 1.1615x over previous
//
#include <hip/hip_runtime.h>
#include <math.h>

// BiLSTM fused: B=512, T=200, E=H=128, 2 layers, bidir, residual on layer 1,
// out = 0.5*(fw+bw).  Per scan step: z = W*x(t) + U*h(t-1) + b all in MFMA;
// h exchanged via LDS with raw s_barrier + lgkmcnt(0) (vmcnt never drained).
// Round 13 = round 5 verbatim (empirical optimum: 618 us; every subsequent
// touch of the scan regressed) + cvt_x/prep_w merged into one launch.
//   - sigma LUT in LDS (8192 entries, [-16,16), NN): all 5 nonlinearities are
//     sigma lookups (tanh = 2*sigma(2x)-1, g-gate weights prescaled x2).
//   - cross-step overlap: while gates(z(t)) run, the h-independent
//     z(t+1) = b + W*x(t+1) MFMAs issue (double accumulator ping-pong).
// Structural note (12-round evidence): step time ~3500 cyc is barrier-
// lockstep latency-bound, not pipe-bound; parallelism capped at 64 blocks.

typedef _Float16 f16;
typedef _Float16 f16x2 __attribute__((ext_vector_type(2)));
typedef _Float16 f16x4 __attribute__((ext_vector_type(4)));
typedef _Float16 f16x8 __attribute__((ext_vector_type(8)));
typedef float    f32x4 __attribute__((ext_vector_type(4)));

#define B_   512
#define T_   200
#define E_   128
#define H_   128
#define G4_  512
#define M_   (B_*T_)   // 102400
#define LUTN 8192      // sigma table entries over [-16,16)

static __device__ __forceinline__ void lgkm_barrier() {
  asm volatile("s_waitcnt lgkmcnt(0)" ::: "memory");
  __builtin_amdgcn_s_barrier();
}

// ---------- prep: x fp32 -> f16  AND  W,U -> [slab][512][128] f16 ----------
// blocks 0..2047: x conversion (grid-stride, stride fixed at 2048*256).
// blocks 2048..2055: weight transpose slabs (4 of W then 4 of U); g-gate
// rows (cols 256..383) prescaled x2 so tanh(zg) = 2*sigma(zg') - 1.
__global__ __launch_bounds__(256)
void prep_all(const float* __restrict__ x, f16* __restrict__ xh,
              const float* __restrict__ W, const float* __restrict__ U,
              f16* __restrict__ Wt, f16* __restrict__ Ut) {
  const int bx = blockIdx.x;
  if (bx < 2048) {
    const int n8 = M_ * E_ / 8;
    for (int i = bx * 256 + threadIdx.x; i < n8; i += 2048 * 256) {
      const float4 a = ((const float4*)x)[i * 2];
      const float4 b = ((const float4*)x)[i * 2 + 1];
      f16x8 v;
      v[0] = (f16)a.x; v[1] = (f16)a.y; v[2] = (f16)a.z; v[3] = (f16)a.w;
      v[4] = (f16)b.x; v[5] = (f16)b.y; v[6] = (f16)b.z; v[7] = (f16)b.w;
      *(f16x8*)(xh + (size_t)i * 8) = v;
    }
  } else {
    const int m = bx - 2048;                    // 0..7
    const float* s = (m < 4 ? W + (size_t)m * E_ * G4_ : U + (size_t)(m - 4) * E_ * G4_);
    f16* d        = (m < 4 ? Wt + (size_t)m * E_ * G4_ : Ut + (size_t)(m - 4) * E_ * G4_);
    for (int i = threadIdx.x; i < E_ * G4_; i += 256) {
      const int k = i >> 9, g = i & 511;
      float v = s[i];
      if ((g >> 7) == 2) v *= 2.f;
      d[(size_t)g * E_ + k] = (f16)v;
    }
  }
}

// ---------- fused recurrent scan ----------
// grid 64: dir = bx>>5, rows [R0, R0+16).  block 512 = 8 waves.
// Wave wv owns gate-cols {g*128 + wv*16 + c}.  Lane l: batch row l&15,
// kg = l>>4, output cells kg*4+i of hidden slice [wv*16, wv*16+16).
template <int LAYER>
__global__ __launch_bounds__(512, 2)
void scan_fused(const f16* __restrict__ in,    // L0: xh [M][128]; L1: h0 [2][M][128]
                const f16* __restrict__ Utl,   // [2][512][128] (transposed, g x2)
                const f16* __restrict__ Wtl,   // [2][512][128] (transposed, g x2)
                const float* __restrict__ bl,  // [2][512] this layer (raw)
                const f16* __restrict__ res,   // L1: h0 [2][M][128]
                f16* __restrict__ hout)        // [2][M][128]
{
  __shared__ float lut[LUTN];
  __shared__ f16 hsh[2][16][136];

  const int tid  = threadIdx.x;
  const int lane = tid & 63;
  const int wv   = tid >> 6;
  const int row  = lane & 15;
  const int kg   = lane >> 4;
  const int bx   = blockIdx.x;
  const int dir  = bx >> 5;
  const int R0   = (bx & 31) * 16;
  const int coff = wv * 16 + kg * 4;

  const f16* Ud = Utl + (size_t)dir * G4_ * E_;
  const f16* Wd = Wtl + (size_t)dir * G4_ * E_;
  const float* bd = bl + (size_t)dir * G4_;
  const f16* ind  = in + (LAYER == 1 ? (size_t)dir * M_ * H_ : 0);
  f16* houtd      = hout + (size_t)dir * M_ * H_;

  // fill sigma LUT: lut[i] = sigma((i - 4096)/256)
  for (int i = tid; i < LUTN; i += 512) {
    const float xx = (float)(i - LUTN / 2) * (1.f / 256.f);
    lut[i] = 1.f / (1.f + expf(-xx));
  }
  // zero h(-1)
  for (int i = tid; i < 2 * 16 * 136; i += 512) ((f16*)hsh)[i] = (f16)0.f;

  // stationary A-frags (vector loads from pre-transposed f16)
  f16x8 aU[4][4], aW[4][4];
#pragma unroll
  for (int g = 0; g < 4; ++g) {
    const size_t gcol = (size_t)(g * 128 + wv * 16 + row) * E_;
#pragma unroll
    for (int kk = 0; kk < 4; ++kk) {
      aU[g][kk] = *(const f16x8*)(Ud + gcol + kk * 32 + kg * 8);
      aW[g][kk] = *(const f16x8*)(Wd + gcol + kk * 32 + kg * 8);
    }
  }
  // bias (g-gate x2); MFMA C-init each step
  f32x4 zb[4];
#pragma unroll
  for (int g = 0; g < 4; ++g) {
#pragma unroll
    for (int i = 0; i < 4; ++i) {
      const float v = bd[g * 128 + coff + i];
      zb[g][i] = (g == 2) ? 2.f * v : v;
    }
  }

  const int t0 = dir ? (T_ - 1) : 0;
  const int ts = dir ? -1 : 1;

  const f16* inrow  = ind + (size_t)(R0 + row) * T_ * E_;
  const f16* resrow = (LAYER == 1)
      ? res + (size_t)dir * M_ * H_ + (size_t)(R0 + row) * T_ * H_ : nullptr;
  f16* outrow = houtd + (size_t)(R0 + row) * T_ * H_;

  float cc0 = 0.f, cc1 = 0.f, cc2 = 0.f, cc3 = 0.f;

  // prologue loads: x(t0) (consumed below), x(t0+ts), x(t0+2ts)
  f16x8 xP[4], xA[4], xB[4];
  f16x4 rvA = {}, rvB = {};
#pragma unroll
  for (int kk = 0; kk < 4; ++kk) {
    xP[kk] = *(const f16x8*)(inrow + (long)t0 * E_ + kk * 32 + kg * 8);
    xA[kk] = *(const f16x8*)(inrow + (long)(t0 + ts) * E_ + kk * 32 + kg * 8);
    xB[kk] = *(const f16x8*)(inrow + (long)(t0 + 2 * ts) * E_ + kk * 32 + kg * 8);
  }
  if (LAYER == 1) {
    rvA = *(const f16x4*)(resrow + (long)t0 * H_ + coff);
    rvB = *(const f16x4*)(resrow + (long)(t0 + ts) * H_ + coff);
  }

  lgkm_barrier();   // lut + hsh-zero visible

  // zA = b + W*x(t0)
  f32x4 zA[4], zB[4];
#pragma unroll
  for (int g = 0; g < 4; ++g) zA[g] = zb[g];
#pragma unroll
  for (int kk = 0; kk < 4; ++kk) {
    zA[0] = __builtin_amdgcn_mfma_f32_16x16x32_f16(aW[0][kk], xP[kk], zA[0], 0, 0, 0);
    zA[1] = __builtin_amdgcn_mfma_f32_16x16x32_f16(aW[1][kk], xP[kk], zA[1], 0, 0, 0);
    zA[2] = __builtin_amdgcn_mfma_f32_16x16x32_f16(aW[2][kk], xP[kk], zA[2], 0, 0, 0);
    zA[3] = __builtin_amdgcn_mfma_f32_16x16x32_f16(aW[3][kk], xP[kk], zA[3], 0, 0, 0);
  }

  // step: complete zc(t) with U*h(t-1), run gates; meanwhile build
  // zn(t+1) = b + W*x(t+1) (h-independent; fills gate-phase bubbles).
  auto step = [&](f32x4 (&zc)[4], f32x4 (&zn)[4], f16x8 (&xn)[4], f16x4& rv,
                  int s, int rp, int wp) {
    const int t = t0 + s * ts;

    // h(t-1) from LDS
    f16x8 hf[4];
#pragma unroll
    for (int kk = 0; kk < 4; ++kk) hf[kk] = *(const f16x8*)&hsh[rp][row][kk * 32 + kg * 8];

    // zc += U*h(t-1)
#pragma unroll
    for (int kk = 0; kk < 4; ++kk) {
      zc[0] = __builtin_amdgcn_mfma_f32_16x16x32_f16(aU[0][kk], hf[kk], zc[0], 0, 0, 0);
      zc[1] = __builtin_amdgcn_mfma_f32_16x16x32_f16(aU[1][kk], hf[kk], zc[1], 0, 0, 0);
      zc[2] = __builtin_amdgcn_mfma_f32_16x16x32_f16(aU[2][kk], hf[kk], zc[2], 0, 0, 0);
      zc[3] = __builtin_amdgcn_mfma_f32_16x16x32_f16(aU[3][kk], hf[kk], zc[3], 0, 0, 0);
    }

    // build zn = b + W*x(t+1)  (independent of h)
#pragma unroll
    for (int g = 0; g < 4; ++g) zn[g] = zb[g];
#pragma unroll
    for (int kk = 0; kk < 4; ++kk) {
      zn[0] = __builtin_amdgcn_mfma_f32_16x16x32_f16(aW[0][kk], xn[kk], zn[0], 0, 0, 0);
      zn[1] = __builtin_amdgcn_mfma_f32_16x16x32_f16(aW[1][kk], xn[kk], zn[1], 0, 0, 0);
      zn[2] = __builtin_amdgcn_mfma_f32_16x16x32_f16(aW[2][kk], xn[kk], zn[2], 0, 0, 0);
      zn[3] = __builtin_amdgcn_mfma_f32_16x16x32_f16(aW[3][kk], xn[kk], zn[3], 0, 0, 0);
    }

    // reload xn <- x(t+3ts) (consumed at s+2; buffer guards make OOB safe)
    {
      const f16* p = inrow + (long)(t + 3 * ts) * E_;
#pragma unroll
      for (int kk = 0; kk < 4; ++kk) xn[kk] = *(const f16x8*)(p + kk * 32 + kg * 8);
    }
    float rvf[4];
    if (LAYER == 1) {
#pragma unroll
      for (int i = 0; i < 4; ++i) rvf[i] = (float)rv[i];
      rv = *(const f16x4*)(resrow + (long)(t + 2 * ts) * H_ + coff);
    }

    // gates via sigma-LUT (all 5 nonlinearities)
    auto lidx = [](float u) -> int {
      u = fminf(fmaxf(u, 0.f), (float)(LUTN - 1));
      return (int)u;
    };
    float hv[4];
#pragma unroll
    for (int i = 0; i < 4; ++i) {
      const float ig = lut[lidx(fmaf(zc[0][i], 256.f, (float)(LUTN / 2)))];
      const float fg = lut[lidx(fmaf(zc[1][i], 256.f, (float)(LUTN / 2)))];
      const float gg = fmaf(2.f, lut[lidx(fmaf(zc[2][i], 256.f, (float)(LUTN / 2)))], -1.f);
      const float og = lut[lidx(fmaf(zc[3][i], 256.f, (float)(LUTN / 2)))];
      cc0 = cc0;  // no-op; keep structure identical
      float c = (i == 0 ? cc0 : i == 1 ? cc1 : i == 2 ? cc2 : cc3);
      c = fmaf(fg, c, ig * gg);
      const float th = fmaf(2.f, lut[lidx(fmaf(c, 512.f, (float)(LUTN / 2)))], -1.f);
      hv[i] = og * th;
      if (i == 0) cc0 = c; else if (i == 1) cc1 = c; else if (i == 2) cc2 = c; else cc3 = c;
    }

    f16x4 hp;
#pragma unroll
    for (int i = 0; i < 4; ++i) hp[i] = (f16)hv[i];
    *(f16x4*)&hsh[wp][row][coff] = hp;

    f16* orow = outrow + (long)t * H_ + coff;
    if (LAYER == 0) {
      *(f16x4*)orow = hp;
    } else {
      f16x4 o;
#pragma unroll
      for (int i = 0; i < 4; ++i) o[i] = (f16)(0.5f * (hv[i] + rvf[i]));
      *(f16x4*)orow = o;
    }

    lgkm_barrier();   // h(t) visible; vmcnt NOT drained
  };

  for (int k = 0; k < T_ / 2; ++k) {
    step(zA, zB, xA, rvA, 2 * k,     0, 1);
    step(zB, zA, xB, rvB, 2 * k + 1, 1, 0);
  }
}

__global__ __launch_bounds__(256)
void final_add(const f16* __restrict__ a, const f16* __restrict__ b,
               float* __restrict__ o)
{
  const int n8 = M_ * H_ / 8;
  for (int i = blockIdx.x * 256 + threadIdx.x; i < n8; i += gridDim.x * 256) {
    const f16x8 va = *(const f16x8*)(a + (size_t)i * 8);
    const f16x8 vb = *(const f16x8*)(b + (size_t)i * 8);
    float4 o0, o1;
    o0.x = (float)va[0] + (float)vb[0];  o0.y = (float)va[1] + (float)vb[1];
    o0.z = (float)va[2] + (float)vb[2];  o0.w = (float)va[3] + (float)vb[3];
    o1.x = (float)va[4] + (float)vb[4];  o1.y = (float)va[5] + (float)vb[5];
    o1.z = (float)va[6] + (float)vb[6];  o1.w = (float)va[7] + (float)vb[7];
    *(float4*)(o + (size_t)i * 8)     = o0;
    *(float4*)(o + (size_t)i * 8 + 4) = o1;
  }
}

extern "C" void kernel_launch(void* const* d_in, const int* in_sizes, int n_in,
                              void* d_out, int out_size, void* d_ws, size_t ws_size,
                              hipStream_t stream) {
  const float* x = (const float*)d_in[0];
  const float* W = (const float*)d_in[1];  // [2][2][128][512]
  const float* U = (const float*)d_in[2];  // [2][2][128][512]
  const float* b = (const float*)d_in[3];  // [2][2][512]
  float* out = (float*)d_out;

  char* ws = (char*)d_ws;
  // 2KB guards around xh/h0/h1: register pipelines prefetch up to 3
  // timesteps (<=768B) past either end of a row.
  f16* xh = (f16*)(ws + 2048);                     // [M][128]    26.2 MB
  f16* h0 = xh + (size_t)M_ * E_ + 1024;           // [2][M][128] 52.4 MB (+2KB guard)
  f16* h1 = h0 + (size_t)2 * M_ * H_ + 1024;       // [2][M][128] 52.4 MB (+2KB guard)
  f16* Wt = h1 + (size_t)2 * M_ * H_ + 1024;       // [2][2][512][128] 1 MB
  f16* Ut = Wt + (size_t)4 * G4_ * E_;             // [2][2][512][128] 1 MB

  const size_t WTL = (size_t)2 * G4_ * E_;         // f16 per layer of Wt/Ut
  const size_t BL  = 2 * G4_;

  prep_all<<<dim3(2056), 256, 0, stream>>>(x, xh, W, U, Wt, Ut);
  scan_fused<0><<<dim3(64), 512, 0, stream>>>(xh, Ut, Wt, b, nullptr, h0);
  scan_fused<1><<<dim3(64), 512, 0, stream>>>(h0, Ut + WTL, Wt + WTL, b + BL, h0, h1);
  final_add<<<dim3(2048), 256, 0, stream>>>(h1, h1 + (size_t)M_ * H_, out);
}